// Round 9
// baseline (161.386 us; speedup 1.0000x reference)
//
#include <hip/hip_runtime.h>
#include <hip/hip_bf16.h>
#include <float.h>

#define Bc 32
#define Nc 512
#define Dc 128
#define Hc 8
#define DKc 16
#define Ec 128
#define LOG2E 1.44269504088896340736f
#define SCLAMP 80.0f

typedef __attribute__((ext_vector_type(4))) short s16x4;
typedef __attribute__((ext_vector_type(8))) short s16x8;
typedef __attribute__((ext_vector_type(4))) float f32x4;

union BFU { __hip_bfloat16 b; short s; };
static __device__ inline short f2bf(float f) { BFU u; u.b = __float2bfloat16(f); return u.s; }
static __device__ inline s16x4 pack4(float a, float b, float c, float d) {
  s16x4 r; r[0] = f2bf(a); r[1] = f2bf(b); r[2] = f2bf(c); r[3] = f2bf(d); return r;
}

#if __has_builtin(__builtin_amdgcn_exp2f)
#define EXP2F(x) __builtin_amdgcn_exp2f(x)
#else
#define EXP2F(x) exp2f(x)
#endif

// D = A*B + C for 16x16x16 bf16. A[m=l&15][k=(l>>4)*4+i]; B[k=(l>>4)*4+i][n=l&15];
// C/D: col(n)=l&15, row(m)=(l>>4)*4+reg.
static __device__ inline f32x4 mfma16(s16x4 a, s16x4 b, f32x4 c) {
#if __has_builtin(__builtin_amdgcn_mfma_f32_16x16x16bf16_1k)
  return __builtin_amdgcn_mfma_f32_16x16x16bf16_1k(a, b, c, 0, 0, 0);
#else
  int lane = threadIdx.x & 63;
  int g = lane >> 4, base = lane & 15;
  int src0 = (base + 32 * g) & 63;
  int src1 = (base + 32 * g + 16) & 63;
  int ax = ((int*)&a)[0], ay = ((int*)&a)[1];
  int bx = ((int*)&b)[0], by = ((int*)&b)[1];
  int A0 = __shfl(ax, src0), A1 = __shfl(ay, src0);
  int A2 = __shfl(ax, src1), A3 = __shfl(ay, src1);
  int B0 = __shfl(bx, src0), B1 = __shfl(by, src0);
  int B2 = __shfl(bx, src1), B3 = __shfl(by, src1);
  if (g >= 2) { A0 = A1 = A2 = A3 = 0; B0 = B1 = B2 = B3 = 0; }
  s16x8 A8, B8;
  ((int*)&A8)[0] = A0; ((int*)&A8)[1] = A1; ((int*)&A8)[2] = A2; ((int*)&A8)[3] = A3;
  ((int*)&B8)[0] = B0; ((int*)&B8)[1] = B1; ((int*)&B8)[2] = B2; ((int*)&B8)[3] = B3;
  return __builtin_amdgcn_mfma_f32_16x16x32_bf16(A8, B8, c, 0, 0, 0);
#endif
}

// ---- prep: weight converter (0..255) + mask detector (256) ----
__global__ __launch_bounds__(256) void prep_conv(
    const float* __restrict__ Wq, const float* __restrict__ Wk, const float* __restrict__ Wv,
    const float* __restrict__ Wo,
    const unsigned char* __restrict__ m, int* __restrict__ flag,
    short* __restrict__ Wt, short* __restrict__ Wob)
{
  int blk = blockIdx.x;
  int t = threadIdx.x;
  if (blk == 256) {   // detector (single-writer)
    __shared__ int red[4];
    int any = 0;
    for (int u = t; u < 16384; u += 256)
      if ((u & 3) != 0 && m[u] != 0) any = 1;
    unsigned long long bal = __ballot(any != 0);
    if ((t & 63) == 0) red[t >> 6] = (bal != 0ULL) ? 1 : 0;
    __syncthreads();
    if (t == 0) *flag = red[0] | red[1] | red[2] | red[3];
    return;
  }
  int o = blk * 256 + t;
  if (o < 49152) {
    int mat = o >> 14, r = o & 16383;
    int hk = r >> 7, d = r & 127;
    const float* src = (mat == 0) ? Wq : ((mat == 1) ? Wk : Wv);
    Wt[o] = f2bf(src[(hk >> 4) * 2048 + d * 16 + (hk & 15)]);
  } else {
    int o2 = o - 49152;
    int et = o2 >> 11, s = (o2 >> 8) & 7, lane = (o2 >> 2) & 63, i = o2 & 3;
    Wob[o2] = f2bf(Wo[(s * 16 + (lane >> 4) * 4 + i) * 128 + et * 16 + (lane & 15)]);
  }
}

// ---- celltab: 4096-cell uniform PWL table over [-8,8), step 1/256 ----
// Per cell: exact MLP segment at cell midpoint. tabI[c*8+h] = pack(bf16(f(m)*L)<<16 | bf16(a*L)).
// wl layout: W1[0:16) b1[16:32) W2[32:288) b2[288:304) W3[304:432) b3[432:440)
__global__ __launch_bounds__(256, 1) void celltab(
    const float* __restrict__ mW1, const float* __restrict__ mb1,
    const float* __restrict__ mW2, const float* __restrict__ mb2,
    const float* __restrict__ mW3, const float* __restrict__ mb3,
    int* __restrict__ tabI)
{
  __shared__ float wl[440];
  int t = threadIdx.x;
  for (int u = t; u < 440; u += 256) {
    float v;
    if (u < 16) v = mW1[u];
    else if (u < 32)  v = mb1[u - 16];
    else if (u < 288) v = mW2[u - 32];
    else if (u < 304) v = mb2[u - 288];
    else if (u < 432) v = mW3[u - 304];
    else v = mb3[u - 432];
    wl[u] = v;
  }
  __syncthreads();
  int c = blockIdx.x * 256 + t;
  float m = fmaf((float)c, 0.00390625f, -7.998046875f);   // -8 + 1/512 + c/256

  float pre[16];
  #pragma unroll
  for (int u = 0; u < 16; ++u) pre[u] = fmaf(m, wl[u], wl[16 + u]);

  float a2[16], v2[16];
  #pragma unroll
  for (int v = 0; v < 16; ++v) { a2[v] = 0.f; v2[v] = wl[288 + v]; }
  #pragma unroll
  for (int u = 0; u < 16; ++u) {
    bool act = pre[u] > 0.f;
    float w1 = act ? wl[u] : 0.f;
    float pp = act ? pre[u] : 0.f;
    #pragma unroll
    for (int v = 0; v < 16; ++v) {
      float w2 = wl[32 + u * 16 + v];
      a2[v] = fmaf(w1, w2, a2[v]);
      v2[v] = fmaf(pp, w2, v2[v]);
    }
  }

  float ah[8], fh[8];
  #pragma unroll
  for (int h = 0; h < 8; ++h) { ah[h] = 0.f; fh[h] = wl[432 + h]; }
  #pragma unroll
  for (int v = 0; v < 16; ++v) {
    bool act = v2[v] > 0.f;
    float av = act ? a2[v] : 0.f;
    float vv = act ? v2[v] : 0.f;
    #pragma unroll
    for (int h = 0; h < 8; ++h) {
      float w3 = wl[304 + v * 8 + h];
      ah[h] = fmaf(av, w3, ah[h]);
      fh[h] = fmaf(vv, w3, fh[h]);
    }
  }
  #pragma unroll
  for (int h = 0; h < 8; ++h) {
    int ab = (int)(unsigned short)(f2bf(ah[h] * LOG2E));
    int fb = ((int)f2bf(fh[h] * LOG2E)) << 16;
    tabI[(c << 3) + h] = fb | ab;
  }
}

// ---- kernel A: QKV projection via MFMA (unchanged, verified) ----
__global__ __launch_bounds__(256, 4) void qkv4(
    const float* __restrict__ q, const short* __restrict__ Wt,
    short* __restrict__ Qb, short* __restrict__ Kb, short* __restrict__ Vt)
{
  __shared__ short qs[16][136];
  int blk = blockIdx.x;
  int b = blk >> 5;
  int rt = (blk & 31) << 4;
  int t = threadIdx.x;
  int wid = t >> 6, lane = t & 63;
  int lq = lane & 15, lg = lane >> 4;

  #pragma unroll
  for (int it = 0; it < 2; ++it) {
    int u = t + it * 256;
    int row = u >> 5, c4 = (u & 31) << 2;
    float4 v = *(const float4*)&q[((((b << 9) + rt + row) << 7)) + c4];
    *(s16x4*)&qs[row][c4] = pack4(v.x, v.y, v.z, v.w);
  }
  __syncthreads();

  s16x4 af[8];
  #pragma unroll
  for (int ks = 0; ks < 8; ++ks)
    af[ks] = *(const s16x4*)&qs[lq][ks * 16 + lg * 4];

  #pragma unroll 1
  for (int pj = 0; pj < 3; ++pj) {
    const short* Wm = Wt + pj * 16384;
    #pragma unroll
    for (int c2 = 0; c2 < 2; ++c2) {
      int ct = wid * 2 + c2;
      f32x4 acc = (f32x4)0.f;
      #pragma unroll
      for (int ks = 0; ks < 8; ++ks) {
        s16x4 bf = *(const s16x4*)&Wm[(ct * 16 + lq) * 128 + ks * 16 + lg * 4];
        acc = mfma16(af[ks], bf, acc);
      }
      if (pj == 0) {
        s16x4 pk = pack4(acc[0] * (0.25f * LOG2E), acc[1] * (0.25f * LOG2E),
                         acc[2] * (0.25f * LOG2E), acc[3] * (0.25f * LOG2E));
        #pragma unroll
        for (int r = 0; r < 4; ++r)
          Qb[(ct << 18) + (b << 13) + ((rt + lg * 4 + r) << 4) + lq] = pk[r];
      } else if (pj == 1) {
        s16x4 pk = pack4(acc[0], acc[1], acc[2], acc[3]);
        #pragma unroll
        for (int r = 0; r < 4; ++r)
          Kb[(ct << 18) + (b << 13) + ((rt + lg * 4 + r) << 4) + lq] = pk[r];
      } else {
        s16x4 pk = pack4(acc[0], acc[1], acc[2], acc[3]);
        *(s16x4*)&Vt[(ct << 18) + (((b << 4) + lq) << 9) + rt + lg * 4] = pk;
      }
    }
  }
}

// ---- kernel B: table-lookup edge-bias + masked softmax attn + MFMA out-proj ----
// Main loop uses NO LDS. Epilogue overlay: d2 [4][128][17] f32 @0 + psum [4][8][16] @34816.
__global__ __launch_bounds__(256, 4) void attn9(
    const float* __restrict__ edge, const unsigned char* __restrict__ maskB,
    const int* __restrict__ flag,
    const short* __restrict__ Qb, const short* __restrict__ Kb, const short* __restrict__ Vt,
    const short* __restrict__ Wob,
    const int* __restrict__ tabI,
    float* __restrict__ out)
{
  __shared__ __align__(16) char smem[36864];

  int t = threadIdx.x;
  int wid = t >> 6, lane = t & 63;
  int lq = lane & 15, lg = lane >> 4;
  int b = blockIdx.x >> 5;
  int qt = (blockIdx.x & 31) << 4;
  int mflag = *flag;

  float* d2L = (float*)smem;               // epilogue overlay [4][128][17]
  float* psL = (float*)(smem + 34816);     // [4][8][16]

  const short* Kl = Kb + (b << 13) + (lq << 4) + (lg << 2);
  const short* Vl = Vt + (((b << 4) + lq) << 9) + (lg << 2);
  const short* Ql = Qb + (b << 13) + ((qt + lq) << 4) + (lg << 2);
  unsigned mbase = (((b << 9) + qt + lq) << 9) + (lg << 2);

  s16x4 qf[8];
  #pragma unroll
  for (int h = 0; h < 8; ++h) qf[h] = *(const s16x4*)(Ql + (h << 18));

  f32x4 oacc[8];
  float psum[8];
  #pragma unroll
  for (int h = 0; h < 8; ++h) { oacc[h] = (f32x4)0.f; psum[h] = 0.f; }

  // prologue: chunk 0 edge + mask
  int jb = wid << 4;
  float4 ev = *(const float4*)&edge[mbase + jb];
  int4 mkv;
  if (mflag) {
    uchar4 u = *(const uchar4*)&maskB[mbase + jb];
    mkv.x = u.x; mkv.y = u.y; mkv.z = u.z; mkv.w = u.w;
  } else {
    mkv = *(const int4*)&((const int*)maskB)[mbase + jb];
  }

#define DOHEAD(h) { \
    f32x4 sc; \
    sc[0] = fmaf(__int_as_float(cf[0][h] << 16), em0, __int_as_float(cf[0][h] & 0xffff0000)); \
    sc[1] = fmaf(__int_as_float(cf[1][h] << 16), em1, __int_as_float(cf[1][h] & 0xffff0000)); \
    sc[2] = fmaf(__int_as_float(cf[2][h] << 16), em2, __int_as_float(cf[2][h] & 0xffff0000)); \
    sc[3] = fmaf(__int_as_float(cf[3][h] << 16), em3, __int_as_float(cf[3][h] & 0xffff0000)); \
    sc = mfma16(kf[h], qf[h], sc); \
    s16x4 vf = *(const s16x4*)(Vl + ((h) << 18) + jb); \
    float p0 = mkv.x ? 0.f : EXP2F(fminf(sc[0], SCLAMP)); \
    float p1 = mkv.y ? 0.f : EXP2F(fminf(sc[1], SCLAMP)); \
    float p2 = mkv.z ? 0.f : EXP2F(fminf(sc[2], SCLAMP)); \
    float p3 = mkv.w ? 0.f : EXP2F(fminf(sc[3], SCLAMP)); \
    psum[h] += (p0 + p1) + (p2 + p3); \
    s16x4 pf = pack4(p0, p1, p2, p3); \
    oacc[h] = mfma16(vf, pf, oacc[h]); }

  #pragma unroll 1
  for (int cc = 0; cc < 8; ++cc) {
    jb = ((cc << 2) | wid) << 4;

    // PWL cell index + in-cell offset for this chunk's 4 edges
    float fx0 = fminf(fmaxf(fmaf(ev.x, 256.f, 2048.f), 0.f), 4095.f);
    float fx1 = fminf(fmaxf(fmaf(ev.y, 256.f, 2048.f), 0.f), 4095.f);
    float fx2 = fminf(fmaxf(fmaf(ev.z, 256.f, 2048.f), 0.f), 4095.f);
    float fx3 = fminf(fmaxf(fmaf(ev.w, 256.f, 2048.f), 0.f), 4095.f);
    int ix0 = (int)fx0, ix1 = (int)fx1, ix2 = (int)fx2, ix3 = (int)fx3;
    float em0 = ev.x - fmaf((float)ix0, 0.00390625f, -7.998046875f);
    float em1 = ev.y - fmaf((float)ix1, 0.00390625f, -7.998046875f);
    float em2 = ev.z - fmaf((float)ix2, 0.00390625f, -7.998046875f);
    float em3 = ev.w - fmaf((float)ix3, 0.00390625f, -7.998046875f);
    const int4* tp0 = (const int4*)(tabI + (ix0 << 3));
    const int4* tp1 = (const int4*)(tabI + (ix1 << 3));
    const int4* tp2 = (const int4*)(tabI + (ix2 << 3));
    const int4* tp3 = (const int4*)(tabI + (ix3 << 3));
    int4 L0 = tp0[0], H0 = tp0[1];
    int4 L1 = tp1[0], H1 = tp1[1];
    int4 L2 = tp2[0], H2 = tp2[1];
    int4 L3 = tp3[0], H3 = tp3[1];
    int cf[4][8];
    cf[0][0] = L0.x; cf[0][1] = L0.y; cf[0][2] = L0.z; cf[0][3] = L0.w;
    cf[0][4] = H0.x; cf[0][5] = H0.y; cf[0][6] = H0.z; cf[0][7] = H0.w;
    cf[1][0] = L1.x; cf[1][1] = L1.y; cf[1][2] = L1.z; cf[1][3] = L1.w;
    cf[1][4] = H1.x; cf[1][5] = H1.y; cf[1][6] = H1.z; cf[1][7] = H1.w;
    cf[2][0] = L2.x; cf[2][1] = L2.y; cf[2][2] = L2.z; cf[2][3] = L2.w;
    cf[2][4] = H2.x; cf[2][5] = H2.y; cf[2][6] = H2.z; cf[2][7] = H2.w;
    cf[3][0] = L3.x; cf[3][1] = L3.y; cf[3][2] = L3.z; cf[3][3] = L3.w;
    cf[3][4] = H3.x; cf[3][5] = H3.y; cf[3][6] = H3.z; cf[3][7] = H3.w;

    s16x4 kf[8];
    #pragma unroll
    for (int h = 0; h < 8; ++h) kf[h] = *(const s16x4*)(Kl + (h << 18) + (jb << 4));

    // prefetch next chunk's edge + mask
    float4 evn; int4 mkn;
    if (cc < 7) {
      int jbn = (((cc + 1) << 2) | wid) << 4;
      evn = *(const float4*)&edge[mbase + jbn];
      if (mflag) {
        uchar4 u = *(const uchar4*)&maskB[mbase + jbn];
        mkn.x = u.x; mkn.y = u.y; mkn.z = u.z; mkn.w = u.w;
      } else {
        mkn = *(const int4*)&((const int*)maskB)[mbase + jbn];
      }
    } else { evn = ev; mkn = mkv; }

    DOHEAD(0) DOHEAD(1) DOHEAD(2) DOHEAD(3)
    DOHEAD(4) DOHEAD(5) DOHEAD(6) DOHEAD(7)

    ev = evn; mkv = mkn;
  }
#undef DOHEAD

  // ---- epilogue: cross-wave psum, normalize, MFMA out-projection, merge ----
  #pragma unroll
  for (int h = 0; h < 8; ++h) {
    float s = psum[h];
    s += __shfl_xor(s, 16);
    s += __shfl_xor(s, 32);
    psum[h] = s;
  }
  if (lg == 0) {
    #pragma unroll
    for (int h = 0; h < 8; ++h) psL[wid * 128 + h * 16 + lq] = psum[h];
  }
  __syncthreads();

  s16x4 obf[8];
  #pragma unroll
  for (int h = 0; h < 8; ++h) {
    float tot = psL[h * 16 + lq] + psL[128 + h * 16 + lq]
              + psL[256 + h * 16 + lq] + psL[384 + h * 16 + lq];
    float inv = (tot > 0.f) ? 1.f / tot : 0.f;
    obf[h] = pack4(oacc[h][0] * inv, oacc[h][1] * inv, oacc[h][2] * inv, oacc[h][3] * inv);
  }

  f32x4 d2a[8];
  #pragma unroll
  for (int et = 0; et < 8; ++et) d2a[et] = (f32x4)0.f;
  #pragma unroll
  for (int s = 0; s < 8; ++s) {
    #pragma unroll
    for (int et = 0; et < 8; ++et) {
      s16x4 wo = *(const s16x4*)&Wob[((et * 8 + s) << 8) + (lane << 2)];
      d2a[et] = mfma16(wo, obf[s], d2a[et]);
    }
  }

  #pragma unroll
  for (int et = 0; et < 8; ++et)
    #pragma unroll
    for (int r = 0; r < 4; ++r)
      d2L[(wid * 128 + et * 16 + lg * 4 + r) * 17 + lq] = d2a[et][r];
  __syncthreads();

  #pragma unroll
  for (int k = 0; k < 2; ++k) {
    int et = wid * 2 + k;
    #pragma unroll
    for (int r = 0; r < 4; ++r) {
      int el = (et * 16 + lg * 4 + r) * 17 + lq;
      float v = d2L[el] + d2L[2176 + el] + d2L[4352 + el] + d2L[6528 + el];
      out[(((b << 9) + qt + lq) << 7) + et * 16 + lg * 4 + r] = v;
    }
  }
}

extern "C" void kernel_launch(void* const* d_in, const int* in_sizes, int n_in,
                              void* d_out, int out_size, void* d_ws, size_t ws_size,
                              hipStream_t stream)
{
  const float* q    = (const float*)d_in[0];
  const unsigned char* mask = (const unsigned char*)d_in[1];
  const float* edge = (const float*)d_in[2];
  const float* Wq   = (const float*)d_in[3];
  const float* Wk   = (const float*)d_in[4];
  const float* Wv   = (const float*)d_in[5];
  const float* Wo   = (const float*)d_in[6];
  const float* mW1  = (const float*)d_in[7];
  const float* mb1  = (const float*)d_in[8];
  const float* mW2  = (const float*)d_in[9];
  const float* mb2  = (const float*)d_in[10];
  const float* mW3  = (const float*)d_in[11];
  const float* mb3  = (const float*)d_in[12];
  float* out = (float*)d_out;

  size_t per = (size_t)Hc * Bc * Nc * DKc;     // 2,097,152 bf16 elems per matrix
  short* Wt  = (short*)d_ws;                   // 49152
  short* Wob = Wt + 49152;                     // 16384
  short* Qb  = Wob + 16384;
  short* Kb  = Qb + per;
  short* Vt  = Kb + per;
  int* tabI  = (int*)(Vt + per);               // 32768 ints (128 KB), 16B-aligned
  int* flag  = tabI + 32768;                   // ~12.8 MB used

  prep_conv<<<dim3(257), dim3(256), 0, stream>>>(Wq, Wk, Wv, Wo, mask, flag, Wt, Wob);
  celltab<<<dim3(16), dim3(256), 0, stream>>>(mW1, mb1, mW2, mb2, mW3, mb3, tabI);
  qkv4<<<dim3(Bc * 32), dim3(256), 0, stream>>>(q, Wt, Qb, Kb, Vt);
  attn9<<<dim3(Bc * 32), dim3(256), 0, stream>>>(edge, mask, flag, Qb, Kb, Vt, Wob,
      tabI, out);
}